// Round 8
// baseline (840.586 us; speedup 1.0000x reference)
//
#include <hip/hip_runtime.h>
#include <math.h>

typedef __attribute__((ext_vector_type(8))) short short8;
typedef __attribute__((ext_vector_type(4))) float f32x4;

#define GLOBAL_AS __attribute__((address_space(1)))
#define LDS_AS __attribute__((address_space(3)))

__device__ __forceinline__ unsigned short f2bf(float f) {
  union { float f; unsigned u; } v; v.f = f;
  unsigned r = v.u + 0x7fffu + ((v.u >> 16) & 1u);
  return (unsigned short)(r >> 16);
}

// fp32 -> bf16 (RNE), 4 elements/thread
__global__ void cvt_f32_to_bf16(const float* __restrict__ in,
                                unsigned short* __restrict__ out, int n4) {
  int i = blockIdx.x * blockDim.x + threadIdx.x;
  if (i < n4) {
    const float4 v = ((const float4*)in)[i];
    ushort4 o;
    o.x = f2bf(v.x); o.y = f2bf(v.y); o.z = f2bf(v.z); o.w = f2bf(v.w);
    ((ushort4*)out)[i] = o;
  }
}

// C = A @ B^T. A:[M][K], B:[N][K] bf16 row-major. 256x256 tile, BK=64, 8 waves.
// v7 == v6 mainline (frozen control) + ABL template hooks for timing ablations:
//   ABL=0: normal (fc1/fc2).
//   ABL=2: "nostage" probe — ds_reads+barriers+lgkm+setprio+MFMA, NO staging,
//          NO vmcnt. Reads stale/uninit LDS (timing-valid, output unused);
//          acc kept live via fsum + asm sink (no C-write, no bias/scale loads).
// Probe duration is recovered from total_dur − baseline (it is too short to
// appear in the top-5 dispatch table). grid=256 (1 WG/CU), NT=24.
// --- v6 schedule (unchanged): one half-tile staged per phase, vmcnt(2)/tile,
// raw asm barriers, sigma'(byte)=byte^((row&7)<<4) swizzle, 0 bank conflicts.
template <int EPI, int ABL = 0>
__global__ __launch_bounds__(512, 2) void gemm256_v7(
    const unsigned short* __restrict__ A, const unsigned short* __restrict__ B,
    const float* __restrict__ bias, const float* __restrict__ scale,
    void* __restrict__ Cout, int M, int N, int K) {
  constexpr int BM = 256, BN = 256;
  __shared__ __attribute__((aligned(16))) unsigned short ldsAll[65536]; // 128 KiB

  const int NT = K >> 6;                 // K-tiles of 64 (even)
  const int nTn = N / BN;
  const int bid = blockIdx.x;
  const int cpx = gridDim.x >> 3;        // grid % 8 == 0 for our shapes
  const int wg = (bid & 7) * cpx + (bid >> 3);   // bijective XCD swizzle
  const int tm = wg / nTn, tn = wg % nTn;

  const int tid = threadIdx.x;
  const int w = tid >> 6, l = tid & 63;
  const int wr = w >> 2, wc = w & 3;     // wave 2x4 -> per-wave 128x64 out
  const int lr = l & 15, g = l >> 4;

  const unsigned short* Ag = A + (size_t)tm * BM * K;
  const unsigned short* Bg = B + (size_t)tn * BN * K;

  // ---- staging source (inverse-sigma'd global, full 128B rows) ----
  const int rowt = tid >> 3;                       // 0..63
  const int colsh = ((((tid & 7) * 16) ^ ((rowt & 7) << 4)) >> 1); // shorts
  const size_t segK = (size_t)64 * K;              // seg1: +64 rows
  const unsigned short* pA0g = Ag + (size_t)rowt * K + colsh;
  const unsigned short* pA1g = Ag + ((size_t)128 + rowt) * K + colsh;
  const unsigned short* pB0g = Bg + (size_t)rowt * K + colsh;
  const unsigned short* pB1g = Bg + ((size_t)128 + rowt) * K + colsh;

  char* const LB = (char*)ldsAll;
  const int wl = w * 1024;               // wave-uniform LDS byte off (+lane*16 HW)

#define BARRIER() asm volatile("s_barrier" ::: "memory")

#define STAGE_AH(tau, h, DB)                                                     \
  if constexpr (ABL == 0 || ABL == 1) {                                          \
    if ((tau) < NT) {                                                            \
      const unsigned short* q_ = ((h) ? pA1g : pA0g) + (size_t)(tau) * 64;       \
      __builtin_amdgcn_global_load_lds((const GLOBAL_AS void*)q_,                \
          (LDS_AS void*)(LB + (DB) * 32768 + (h) * 16384 + wl), 16, 0, 0);       \
      __builtin_amdgcn_global_load_lds((const GLOBAL_AS void*)(q_ + segK),       \
          (LDS_AS void*)(LB + (DB) * 32768 + (h) * 16384 + 8192 + wl), 16, 0, 0);\
    }                                                                            \
  }
#define STAGE_BH(tau, h, SLOT)                                                   \
  if constexpr (ABL == 0 || ABL == 1) {                                          \
    if ((tau) < NT) {                                                            \
      const unsigned short* q_ = ((h) ? pB1g : pB0g) + (size_t)(tau) * 64;       \
      __builtin_amdgcn_global_load_lds((const GLOBAL_AS void*)q_,                \
          (LDS_AS void*)(LB + 65536 + (SLOT) * 16384 + wl), 16, 0, 0);           \
      __builtin_amdgcn_global_load_lds((const GLOBAL_AS void*)(q_ + segK),       \
          (LDS_AS void*)(LB + 65536 + (SLOT) * 16384 + 8192 + wl), 16, 0, 0);    \
    }                                                                            \
  }

  // ---- sigma'd ds_read bases: all offsets compile-time immediates ----
  const int sig0 = (g * 16) ^ ((lr & 7) << 4);         // ks=0 chunk
  const int sig1 = (64 + g * 16) ^ ((lr & 7) << 4);    // ks=1 chunk
  const char* Ab0 = LB + wr * 16384 + lr * 128 + sig0;  // + DB*32768 + m*2048
  const char* Ab1 = LB + wr * 16384 + lr * 128 + sig1;
  const char* Bb0 = LB + 65536 + (wc >> 1) * 16384 + (wc & 1) * 8192 + lr * 128 + sig0;
  const char* Bb1 = LB + 65536 + (wc >> 1) * 16384 + (wc & 1) * 8192 + lr * 128 + sig1;
#define LDA8(KS, DB, m) (*(const short8*)(((KS) ? Ab1 : Ab0) + (DB) * 32768 + (m) * 2048))
#define LDB8(KS, TP, n) (*(const short8*)(((KS) ? Bb1 : Bb0) + (TP) * 32768 + (n) * 2048))

  f32x4 acc[8][4] = {};
  short8 a[4], b[4];

#define OPEN_MFMA(ROW0)                                                          \
  BARRIER();                                                                     \
  asm volatile("s_waitcnt lgkmcnt(0)" ::: "memory");                             \
  __builtin_amdgcn_s_setprio(1);                                                 \
  _Pragma("unroll") for (int m = 0; m < 4; ++m)                                  \
  _Pragma("unroll") for (int n = 0; n < 4; ++n)                                  \
    acc[(ROW0) + m][n] = __builtin_amdgcn_mfma_f32_16x16x32_bf16(                \
        a[m], b[n], acc[(ROW0) + m][n], 0, 0, 0);                                \
  __builtin_amdgcn_s_setprio(0);

// One K-tile, 4 phases, ONE half-tile staged per phase.
#define TILE_BODY(T_, DB_, TP_, SBHI_, SBLO_, FULL_)                             \
  { /* ph0: ks0 m0-3 (8 ds_read) | stage A-lo(t+1) */                            \
    _Pragma("unroll") for (int m = 0; m < 4; ++m) a[m] = LDA8(0, DB_, m);        \
    _Pragma("unroll") for (int n = 0; n < 4; ++n) b[n] = LDB8(0, TP_, n);        \
    STAGE_AH((T_) + 1, 0, (DB_) ^ 1)                                             \
    OPEN_MFMA(0)                                                                 \
    BARRIER();                                                                   \
    /* ph1: ks0 m4-7 (4 ds_read, reuse b) | stage A-hi(t+1) */                   \
    _Pragma("unroll") for (int m = 0; m < 4; ++m) a[m] = LDA8(0, DB_, 4 + m);    \
    STAGE_AH((T_) + 1, 1, (DB_) ^ 1)                                             \
    OPEN_MFMA(4)                                                                 \
    BARRIER();                                                                   \
    /* ph2: ks1 m0-3 (8 ds_read) | stage B-hi(t+1) */                            \
    _Pragma("unroll") for (int m = 0; m < 4; ++m) a[m] = LDA8(1, DB_, m);        \
    _Pragma("unroll") for (int n = 0; n < 4; ++n) b[n] = LDB8(1, TP_, n);        \
    STAGE_BH((T_) + 1, 1, SBHI_)                                                 \
    OPEN_MFMA(0)                                                                 \
    BARRIER();                                                                   \
    /* ph3: ks1 m4-7 (4 ds_read) | stage B-lo(t+2) | counted wait */             \
    _Pragma("unroll") for (int m = 0; m < 4; ++m) a[m] = LDA8(1, DB_, 4 + m);    \
    STAGE_BH((T_) + 2, 0, SBLO_)                                                 \
    OPEN_MFMA(4)                                                                 \
    if constexpr (ABL == 0 || ABL == 1) {                                        \
      if (FULL_) { asm volatile("s_waitcnt vmcnt(2)" ::: "memory"); }            \
      else       { asm volatile("s_waitcnt vmcnt(0)" ::: "memory"); }            \
    }                                                                            \
    BARRIER();                                                                   \
  }

  // prologue (staged variants only): A(0)->dbuf0, Blo(0)->s0, Bhi(0)->s1,
  // Blo(1)->s2; vmcnt(2) publishes tile 0, leaves Blo(1) in flight.
  STAGE_AH(0, 0, 0)
  STAGE_AH(0, 1, 0)
  STAGE_BH(0, 0, 0)
  STAGE_BH(0, 1, 1)
  STAGE_BH(1, 0, 2)
  if constexpr (ABL == 0 || ABL == 1) {
    asm volatile("s_waitcnt vmcnt(2)" ::: "memory");
  }
  BARRIER();

  for (int kt = 0; kt < NT; kt += 2) {
    // tile kt (even): dbuf 0, B slots {0,1}; Bhi(kt+1)->3, Blo(kt+2)->0
    TILE_BODY(kt, 0, 0, 3, 0, (kt + 2 < NT))
    // tile kt+1 (odd): dbuf 1, B slots {2,3}; Bhi(kt+2)->1, Blo(kt+3)->2
    TILE_BODY(kt + 1, 1, 1, 1, 2, (kt + 3 < NT))
  }

  if constexpr (ABL == 0) {
    // epilogue — C/D layout: col = lane&15, row = (lane>>4)*4 + j  [m89/m91]
    const int orow = tm * BM + wr * 128;
    const int ocol = tn * BN + wc * 64;
    const int rsub = g * 4;
#pragma unroll
    for (int n = 0; n < 4; ++n) {
      const int gn = ocol + n * 16 + lr;
      const float bv = bias[gn];
      const float sv = scale[gn];
#pragma unroll
      for (int m = 0; m < 8; ++m) {
#pragma unroll
        for (int j = 0; j < 4; ++j) {
          const int gm = orow + m * 16 + rsub + j;
          float v = (acc[m][n][j] + bv) * sv;
          if (EPI == 0) {
            const float gl = 0.5f * v * (1.0f + erff(v * 0.70710678118654752440f));
            ((unsigned short*)Cout)[(size_t)gm * N + gn] = f2bf(gl);
          } else {
            ((float*)Cout)[(size_t)gm * N + gn] = v;
          }
        }
      }
    }
  } else {
    // timing probe: keep every MFMA live without memory traffic (rule #17)
    float s = 0.f;
#pragma unroll
    for (int m = 0; m < 8; ++m)
#pragma unroll
      for (int n = 0; n < 4; ++n)
#pragma unroll
        for (int j = 0; j < 4; ++j) s += acc[m][n][j];
    asm volatile("" :: "v"(s));
  }
#undef STAGE_AH
#undef STAGE_BH
#undef LDA8
#undef LDB8
#undef OPEN_MFMA
#undef TILE_BODY
#undef BARRIER
}

extern "C" void kernel_launch(void* const* d_in, const int* in_sizes, int n_in,
                              void* d_out, int out_size, void* d_ws, size_t ws_size,
                              hipStream_t stream) {
  const int T = 16384, H = 2048, H2 = 4096;
  const float* x  = (const float*)d_in[0];
  const float* w1 = (const float*)d_in[1];
  const float* b1 = (const float*)d_in[2];
  const float* s1 = (const float*)d_in[3];
  const float* w2 = (const float*)d_in[4];
  const float* b2 = (const float*)d_in[5];
  const float* s2 = (const float*)d_in[6];

  // workspace (bf16): xb 64MiB | w1b 16MiB | w2b 16MiB | h 128MiB  (224 MiB)
  unsigned short* xb  = (unsigned short*)d_ws;
  unsigned short* w1b = xb  + (size_t)T  * H;
  unsigned short* w2b = w1b + (size_t)H2 * H;
  unsigned short* hb  = w2b + (size_t)H  * H2;

  int n4 = T * H / 4;
  cvt_f32_to_bf16<<<(n4 + 255) / 256, 256, 0, stream>>>(x, xb, n4);
  n4 = H2 * H / 4;
  cvt_f32_to_bf16<<<(n4 + 255) / 256, 256, 0, stream>>>(w1, w1b, n4);
  cvt_f32_to_bf16<<<(n4 + 255) / 256, 256, 0, stream>>>(w2, w2b, n4);

  // fc1 + bias + scale + exact GELU -> h (bf16): M=T, N=2H, K=H, grid 1024
  gemm256_v7<0, 0><<<(T / 256) * (H2 / 256), 512, 0, stream>>>(
      xb, w1b, b1, s1, (void*)hb, T, H2, H);
  // fc2 + bias + scale -> y (fp32): M=T, N=H, K=2H, grid 512
  gemm256_v7<1, 0><<<(T / 256) * (H / 256), 512, 0, stream>>>(
      hb, w2b, b2, s2, d_out, T, H, H2);

  // ---- timing ablation (output unused; duration = total - baseline) ----
  // nostage probe: grid 256 (1 WG/CU), NT=24 (K=1536), reads hb (in-bounds,
  // read-only). No stores. T_probe decodes the staging-vs-read/barrier split.
  gemm256_v7<0, 2><<<256, 512, 0, stream>>>(
      hb, hb, b1, s1, nullptr, 4096, 4096, 1536);
}